// Round 1
// 667.505 us; speedup vs baseline: 1.0798x; 1.0798x over previous
//
#include <hip/hip_runtime.h>

#define N_NODES 50000
#define M_PAD   50048          // nodes padded to multiple of 64
#define N_EDGES 800000
#define E_PAD   1000000        // edges padded: each node's segment rounded to x4
#define DIN 256
#define DH  128
#define NL  1000
#define NL_PAD 1024

typedef unsigned short ushort_t;
typedef __attribute__((ext_vector_type(8))) short bf16x8;
typedef __attribute__((ext_vector_type(4))) float f32x4;
typedef __attribute__((ext_vector_type(4))) unsigned int u32x4;

__device__ __forceinline__ ushort_t f32_to_bf16_rne(float f) {
    unsigned int u = __float_as_uint(f);
    unsigned int r = (u + 0x7FFFu + ((u >> 16) & 1u)) >> 16;
    return (ushort_t)r;
}
// packs (lo,hi) f32 -> 2x bf16 in one instr (no builtin on gfx950; inline asm)
__device__ __forceinline__ unsigned cvt_pk_bf16(float lo, float hi) {
    unsigned r;
    asm("v_cvt_pk_bf16_f32 %0, %1, %2" : "=v"(r) : "v"(lo), "v"(hi));
    return r;
}
__device__ __forceinline__ float bf16_lo(unsigned u) { return __uint_as_float(u << 16); }
__device__ __forceinline__ float bf16_hi(unsigned u) { return __uint_as_float(u & 0xFFFF0000u); }

// ---------------- CSR build ----------------

__global__ void count_deg_kernel(const int* __restrict__ dst, int* __restrict__ deg) {
    int e = blockIdx.x * blockDim.x + threadIdx.x;
    if (e < N_EDGES) atomicAdd(&deg[dst[e]], 1);
}

// In-place exclusive scan of deg -> offsets with each degree rounded up to a
// multiple of 4 (so aggregate can run an aligned 4-edge loop with no tail).
// Gap slots are pre-zeroed (src=0, w=0) so they contribute nothing.
__global__ __launch_bounds__(1024) void scan_kernel(int* __restrict__ off) {
    __shared__ int lds[1024];
    const int t = threadIdx.x;
    const int CHN = (N_NODES + 1023) / 1024;  // 49
    const int lo = t * CHN;
    const int hi = (lo + CHN < N_NODES) ? (lo + CHN) : N_NODES;
    int s = 0;
    for (int i = lo; i < hi; ++i) s += (off[i] + 3) & ~3;
    lds[t] = s;
    __syncthreads();
    for (int o = 1; o < 1024; o <<= 1) {
        int v = (t >= o) ? lds[t - o] : 0;
        __syncthreads();
        lds[t] += v;
        __syncthreads();
    }
    int run = (t == 0) ? 0 : lds[t - 1];
    for (int i = lo; i < hi; ++i) {
        int v = off[i];
        off[i] = run;
        run += (v + 3) & ~3;
    }
    if (t == 1023) off[N_NODES] = lds[1023];
}

// Scatter edges into dst-sorted fused arrays; weights interleaved as float2.
__global__ void scatter_kernel(const int* __restrict__ dst, const int* __restrict__ src,
                               const float* __restrict__ self_w, const float* __restrict__ ppi_w,
                               const int* __restrict__ off, int* __restrict__ cur,
                               int* __restrict__ src_s, float2* __restrict__ w2_s) {
    int e = blockIdx.x * blockDim.x + threadIdx.x;
    if (e < N_EDGES) {
        int d = dst[e];
        int p = off[d] + atomicAdd(&cur[d], 1);
        src_s[p] = src[e];
        w2_s[p]  = make_float2(ppi_w[e], self_w[e]);   // (.x = ppi, .y = self)
    }
}

// ---------------- fused B-operand pack (fragment-contiguous) ----------------
// Layout per fragment lane: n = tile*16 + (lane&15), k = chunk*32 + (lane>>4)*8 + j.
// This is simultaneously a valid MFMA *A*-operand holding W^T (rows = out dims),
// which is how the GEMMs below consume it (swapped-operand trick).
__device__ __forceinline__ void pack_one(const float* __restrict__ W, ushort_t* __restrict__ Bp,
                                         int K, int Nreal, int t) {
    const int CHN = K / 32;
    int lane = t & 63;
    int c = (t >> 6) % CHN;
    int nt = (t >> 6) / CHN;
    int n = nt * 16 + (lane & 15);
    int kb = c * 32 + (lane >> 4) * 8;
    ushort_t* p = Bp + (size_t)t * 8;
#pragma unroll
    for (int j = 0; j < 8; ++j)
        p[j] = (n < Nreal) ? f32_to_bf16_rne(W[(size_t)(kb + j) * Nreal + n]) : (ushort_t)0;
}

#define T_IN  ((DH / 16) * (DIN / 32) * 64)        // 4096
#define T_L   ((DH / 16) * (DH / 32) * 64)         // 2048
#define T_OUT ((NL_PAD / 16) * (DH / 32) * 64)     // 16384
#define T_ALL (T_IN + 2 * T_L + T_OUT)             // 24576

__global__ void pack_all_kernel(const float* __restrict__ W_in, const float* __restrict__ W1,
                                const float* __restrict__ W2, const float* __restrict__ W_out,
                                ushort_t* __restrict__ Bp_in, ushort_t* __restrict__ Bp_1,
                                ushort_t* __restrict__ Bp_2, ushort_t* __restrict__ Bp_out) {
    int tid = blockIdx.x * blockDim.x + threadIdx.x;
    if (tid < T_IN) pack_one(W_in, Bp_in, DIN, DH, tid);
    else if (tid < T_IN + T_L) pack_one(W1, Bp_1, DH, DH, tid - T_IN);
    else if (tid < T_IN + 2 * T_L) pack_one(W2, Bp_2, DH, DH, tid - T_IN - T_L);
    else if (tid < T_ALL) pack_one(W_out, Bp_out, DH, NL, tid - T_IN - 2 * T_L);
}

// ---------------- MFMA GEMM, swapped operands ----------------
// D = (W-pack as A) * (node rows as B): D row = output dim, D col = node.
// Each lane therefore holds 4 CONSECUTIVE output dims of one node
// -> float4 / packed-bf16x4 contiguous stores (no partial-line RMW on out).
// grid: (Ndimtiles/(4*G), M_PAD/64), block 256 = 4 waves, no LDS.
// XF32: node-side input is f32 (x), converted in-register via v_cvt_pk_bf16_f32.
template<int K, int G, bool XF32, bool RELU, bool ADD_RES, bool WRITE_F32>
__global__ __launch_bounds__(256) void mfma_gemm_kernel(
    const void* __restrict__ Av, const ushort_t* __restrict__ Bp,
    const float* __restrict__ bias, const ushort_t* __restrict__ res_b,
    float* __restrict__ Cf, ushort_t* __restrict__ Cb,
    int Nreal, int Mstore)
{
    constexpr int CHN = K / 32;
    const int lane = threadIdx.x & 63;
    const int w    = threadIdx.x >> 6;
    const int r0   = blockIdx.y * 64;
    const int lr   = lane & 15;
    const int lq   = lane >> 4;

    // hoist all node-side fragments (B operand); reused across the G dim-tiles
    bf16x8 bf[4][CHN];
    if constexpr (!XF32) {
#pragma unroll
        for (int t = 0; t < 4; ++t) {
            const ushort_t* p = (const ushort_t*)Av + (size_t)(r0 + t * 16 + lr) * K + lq * 8;
#pragma unroll
            for (int c = 0; c < CHN; ++c)
                bf[t][c] = *(const bf16x8*)(p + c * 32);
        }
    } else {
#pragma unroll
        for (int t = 0; t < 4; ++t) {
            const int row = r0 + t * 16 + lr;
            const float* p = (const float*)Av + (size_t)row * K + lq * 8;
            const bool ok = row < N_NODES;
#pragma unroll
            for (int c = 0; c < CHN; ++c) {
                u32x4 uu = {0u, 0u, 0u, 0u};
                if (ok) {
                    float4 f0 = ((const float4*)(p + c * 32))[0];
                    float4 f1 = ((const float4*)(p + c * 32))[1];
                    uu.x = cvt_pk_bf16(f0.x, f0.y);
                    uu.y = cvt_pk_bf16(f0.z, f0.w);
                    uu.z = cvt_pk_bf16(f1.x, f1.y);
                    uu.w = cvt_pk_bf16(f1.z, f1.w);
                }
                bf[t][c] = __builtin_bit_cast(bf16x8, uu);
            }
        }
    }

    for (int g = 0; g < G; ++g) {
        const int dt = (blockIdx.x * G + g) * 4 + w;   // output-dim tile (16 dims)
        f32x4 acc[4] = {f32x4{0,0,0,0}, f32x4{0,0,0,0}, f32x4{0,0,0,0}, f32x4{0,0,0,0}};
#pragma unroll
        for (int c = 0; c < CHN; ++c) {
            bf16x8 afrag = *(const bf16x8*)(Bp + ((size_t)(dt * CHN + c) * 64 + lane) * 8);
#pragma unroll
            for (int t = 0; t < 4; ++t)
                acc[t] = __builtin_amdgcn_mfma_f32_16x16x32_bf16(afrag, bf[t][c], acc[t], 0, 0, 0);
        }

        const int d0 = dt * 16 + lq * 4;               // first of 4 consecutive out dims
        float bv[4];
        if (d0 + 3 < Nreal) {
            const float4 b4 = *(const float4*)(bias + d0);
            bv[0] = b4.x; bv[1] = b4.y; bv[2] = b4.z; bv[3] = b4.w;
        } else {
#pragma unroll
            for (int i = 0; i < 4; ++i) bv[i] = (d0 + i < Nreal) ? bias[d0 + i] : 0.f;
        }
#pragma unroll
        for (int t = 0; t < 4; ++t) {
            const int node = r0 + t * 16 + lr;
            if (node >= Mstore) continue;
            float v[4];
#pragma unroll
            for (int i = 0; i < 4; ++i) {
                v[i] = acc[t][i] + bv[i];
                if (RELU) v[i] = fmaxf(v[i], 0.f);
            }
            if (ADD_RES) {
                const uint2 rr = *(const uint2*)(res_b + (size_t)node * DH + d0);
                v[0] += bf16_lo(rr.x); v[1] += bf16_hi(rr.x);
                v[2] += bf16_lo(rr.y); v[3] += bf16_hi(rr.y);
            }
            if (WRITE_F32) {
                float* q = Cf + (size_t)node * Nreal + d0;
                if (d0 + 3 < Nreal) {
                    float4 o4; o4.x = v[0]; o4.y = v[1]; o4.z = v[2]; o4.w = v[3];
                    *(float4*)q = o4;
                } else {
#pragma unroll
                    for (int i = 0; i < 4; ++i)
                        if (d0 + i < Nreal) q[i] = v[i];
                }
            } else {
                uint2 pp;
                pp.x = cvt_pk_bf16(v[0], v[1]);
                pp.y = cvt_pk_bf16(v[2], v[3]);
                *(uint2*)(Cb + (size_t)node * DH + d0) = pp;
            }
        }
    }
}

// ---------------- aggregation: 1 wave/node, 2 dims/lane, bf16 h ----------------
// Segments are 4-padded: aligned int4 + 2x float4 meta loads, 4 independent
// gathers in flight per iteration, no tail loop.
__global__ __launch_bounds__(256) void aggregate_kernel(
    const ushort_t* __restrict__ hb, const int* __restrict__ off,
    const int* __restrict__ src_s, const float2* __restrict__ w2_s,
    ushort_t* __restrict__ agg_b, ushort_t* __restrict__ res_b)
{
    const int node = blockIdx.x * 4 + (threadIdx.x >> 6);
    const int t = threadIdx.x & 63;
    float aa0 = 0.f, aa1 = 0.f, rr0 = 0.f, rr1 = 0.f;
    if (node < N_NODES) {
        const int lo = off[node], hi = off[node + 1];
        for (int i = lo; i < hi; i += 4) {
            const int4   s4 = *(const int4*)(src_s + i);
            const float4 wa = *(const float4*)(w2_s + i);       // ppi0,self0,ppi1,self1
            const float4 wb = *(const float4*)(w2_s + i + 2);   // ppi2,self2,ppi3,self3
            unsigned u0 = *(const unsigned*)(hb + (size_t)s4.x * DH + 2 * t);
            unsigned u1 = *(const unsigned*)(hb + (size_t)s4.y * DH + 2 * t);
            unsigned u2 = *(const unsigned*)(hb + (size_t)s4.z * DH + 2 * t);
            unsigned u3 = *(const unsigned*)(hb + (size_t)s4.w * DH + 2 * t);
            float a0 = bf16_lo(u0), b0 = bf16_hi(u0);
            float a1 = bf16_lo(u1), b1 = bf16_hi(u1);
            float a2 = bf16_lo(u2), b2 = bf16_hi(u2);
            float a3 = bf16_lo(u3), b3 = bf16_hi(u3);
            aa0 += wa.x * a0 + wa.z * a1 + wb.x * a2 + wb.z * a3;
            aa1 += wa.x * b0 + wa.z * b1 + wb.x * b2 + wb.z * b3;
            rr0 += wa.y * a0 + wa.w * a1 + wb.y * a2 + wb.w * a3;
            rr1 += wa.y * b0 + wa.w * b1 + wb.y * b2 + wb.w * b3;
        }
    }
    unsigned pa = cvt_pk_bf16(aa0, aa1);
    unsigned pr = cvt_pk_bf16(rr0, rr1);
    *(unsigned*)(agg_b + (size_t)node * DH + 2 * t) = pa;
    *(unsigned*)(res_b + (size_t)node * DH + 2 * t) = pr;
}

// ---------------- launch ----------------

extern "C" void kernel_launch(void* const* d_in, const int* in_sizes, int n_in,
                              void* d_out, int out_size, void* d_ws, size_t ws_size,
                              hipStream_t stream) {
    const float* x      = (const float*)d_in[0];
    const int*   src    = (const int*)d_in[1];
    const int*   dst    = (const int*)d_in[2];
    const float* self_w = (const float*)d_in[3];
    const float* ppi_w  = (const float*)d_in[4];
    const float* W_in   = (const float*)d_in[5];
    const float* b_in   = (const float*)d_in[6];
    const float* W1     = (const float*)d_in[7];
    const float* b1     = (const float*)d_in[8];
    const float* W2     = (const float*)d_in[9];
    const float* b2     = (const float*)d_in[10];
    const float* W_out  = (const float*)d_in[11];
    const float* b_out  = (const float*)d_in[12];
    float* out = (float*)d_out;

    char* ws = (char*)d_ws;
    size_t o = 0;
    auto alloc = [&](size_t bytes) { void* p = ws + o; o += (bytes + 255) & ~(size_t)255; return p; };

    ushort_t* hb     = (ushort_t*)alloc((size_t)M_PAD * DH * 2);   // 12.8 MB
    ushort_t* agg_b  = (ushort_t*)alloc((size_t)M_PAD * DH * 2);   // 12.8 MB
    ushort_t* res_b  = (ushort_t*)alloc((size_t)M_PAD * DH * 2);   // 12.8 MB
    int*      off    = (int*)alloc((size_t)(2 * N_NODES + 1) * 4); // off + cur contiguous
    int*      cur    = off + N_NODES + 1;
    int*      src_s  = (int*)alloc((size_t)E_PAD * 4);
    float2*   w2_s   = (float2*)alloc((size_t)E_PAD * 8);
    ushort_t* Bp_in  = (ushort_t*)alloc((size_t)T_IN * 8 * 2);
    ushort_t* Bp_1   = (ushort_t*)alloc((size_t)T_L * 8 * 2);
    ushort_t* Bp_2   = (ushort_t*)alloc((size_t)T_L * 8 * 2);
    ushort_t* Bp_out = (ushort_t*)alloc((size_t)T_OUT * 8 * 2);

    const int EB = (N_EDGES + 255) / 256;

    // CSR build (4-padded segments; gap slots must be zero: src=0, w=0)
    hipMemsetAsync(off, 0, (size_t)(2 * N_NODES + 1) * 4, stream);
    hipMemsetAsync(src_s, 0, (size_t)E_PAD * 4, stream);
    hipMemsetAsync(w2_s, 0, (size_t)E_PAD * 8, stream);
    count_deg_kernel<<<EB, 256, 0, stream>>>(dst, off);
    scan_kernel<<<1, 1024, 0, stream>>>(off);
    scatter_kernel<<<EB, 256, 0, stream>>>(dst, src, self_w, ppi_w, off, cur, src_s, w2_s);

    // weight packs
    pack_all_kernel<<<(T_ALL + 255) / 256, 256, 0, stream>>>(W_in, W1, W2, W_out,
                                                             Bp_in, Bp_1, Bp_2, Bp_out);

    const dim3 g_h(1, M_PAD / 64);   // DH GEMMs: 8 dim-tiles, G=2 x 4 waves
    const dim3 g_o(4, M_PAD / 64);   // out GEMM: 64 dim-tiles, G=4

    // input linear: hb = relu(x @ W_in + b_in)   (reads f32 x directly)
    mfma_gemm_kernel<DIN, 2, true, true, false, false>
        <<<g_h, 256, 0, stream>>>(x, Bp_in, b_in, nullptr, nullptr, hb, DH, M_PAD);

    // layer 1
    aggregate_kernel<<<M_PAD / 4, 256, 0, stream>>>(hb, off, src_s, w2_s, agg_b, res_b);
    mfma_gemm_kernel<DH, 2, false, true, true, false>
        <<<g_h, 256, 0, stream>>>(agg_b, Bp_1, b1, res_b, nullptr, hb, DH, M_PAD);

    // layer 2
    aggregate_kernel<<<M_PAD / 4, 256, 0, stream>>>(hb, off, src_s, w2_s, agg_b, res_b);
    mfma_gemm_kernel<DH, 2, false, true, true, false>
        <<<g_h, 256, 0, stream>>>(agg_b, Bp_2, b2, res_b, nullptr, hb, DH, M_PAD);

    // output linear: out = hb @ W_out + b_out  (float4 contiguous stores)
    mfma_gemm_kernel<DH, 4, false, false, false, true>
        <<<g_o, 256, 0, stream>>>(hb, Bp_out, b_out, nullptr, out, nullptr, NL, N_NODES);
}

// Round 3
// 602.465 us; speedup vs baseline: 1.1964x; 1.1080x over previous
//
#include <hip/hip_runtime.h>

#define N_NODES 50000
#define M_PAD   50048          // nodes padded to multiple of 64
#define N_EDGES 800000
#define E_PAD   1000000        // >= N_EDGES + 3*N_NODES (4-padded segments)
#define DIN 256
#define DH  128
#define NL  1000
#define NL_PAD 1024

typedef unsigned short ushort_t;
typedef __attribute__((ext_vector_type(8))) short bf16x8;
typedef __attribute__((ext_vector_type(4))) float f32x4;
typedef __attribute__((ext_vector_type(4))) unsigned int u32x4;

__device__ __forceinline__ ushort_t f32_to_bf16_rne(float f) {
    unsigned int u = __float_as_uint(f);
    unsigned int r = (u + 0x7FFFu + ((u >> 16) & 1u)) >> 16;
    return (ushort_t)r;
}
// packs (lo,hi) f32 -> 2x bf16 in one instr (no builtin on gfx950; inline asm)
__device__ __forceinline__ unsigned cvt_pk_bf16(float lo, float hi) {
    unsigned r;
    asm("v_cvt_pk_bf16_f32 %0, %1, %2" : "=v"(r) : "v"(lo), "v"(hi));
    return r;
}
__device__ __forceinline__ float bf16_lo(unsigned u) { return __uint_as_float(u << 16); }
__device__ __forceinline__ float bf16_hi(unsigned u) { return __uint_as_float(u & 0xFFFF0000u); }

// ---------------- fused B-operand pack (fragment-contiguous) ----------------
__device__ __forceinline__ void pack_one(const float* __restrict__ W, ushort_t* __restrict__ Bp,
                                         int K, int Nreal, int t) {
    const int CHN = K / 32;
    int lane = t & 63;
    int c = (t >> 6) % CHN;
    int nt = (t >> 6) / CHN;
    int n = nt * 16 + (lane & 15);
    int kb = c * 32 + (lane >> 4) * 8;
    ushort_t* p = Bp + (size_t)t * 8;
#pragma unroll
    for (int j = 0; j < 8; ++j)
        p[j] = (n < Nreal) ? f32_to_bf16_rne(W[(size_t)(kb + j) * Nreal + n]) : (ushort_t)0;
}

#define T_IN  ((DH / 16) * (DIN / 32) * 64)        // 4096
#define T_L   ((DH / 16) * (DH / 32) * 64)         // 2048
#define T_OUT ((NL_PAD / 16) * (DH / 32) * 64)     // 16384
#define T_ALL (T_IN + 2 * T_L + T_OUT)             // 24576
#define EB    ((N_EDGES + 255) / 256)              // 3125 (exact: 3125*256 = 800000)
#define PB    (T_ALL / 256)                        // 96

// ---------------- CSR build ----------------

// blocks [0, EB): degree count.  blocks [EB, EB+PB): weight packing (independent).
__global__ void count_pack_kernel(const int* __restrict__ dst, int* __restrict__ deg,
                                  const float* __restrict__ W_in, const float* __restrict__ W1,
                                  const float* __restrict__ W2, const float* __restrict__ W_out,
                                  ushort_t* __restrict__ Bp_in, ushort_t* __restrict__ Bp_1,
                                  ushort_t* __restrict__ Bp_2, ushort_t* __restrict__ Bp_out) {
    if (blockIdx.x < EB) {
        int e = blockIdx.x * blockDim.x + threadIdx.x;
        if (e < N_EDGES) atomicAdd(&deg[dst[e]], 1);
    } else {
        int tid = (blockIdx.x - EB) * blockDim.x + threadIdx.x;
        if (tid < T_IN) pack_one(W_in, Bp_in, DIN, DH, tid);
        else if (tid < T_IN + T_L) pack_one(W1, Bp_1, DH, DH, tid - T_IN);
        else if (tid < T_IN + 2 * T_L) pack_one(W2, Bp_2, DH, DH, tid - T_IN - T_L);
        else if (tid < T_ALL) pack_one(W_out, Bp_out, DH, NL, tid - T_IN - 2 * T_L);
    }
}

// Wave-atomic segment allocation: replaces the single-block global scan.
// Each node gets a 4-padded disjoint segment (order nondeterministic, contents
// deterministic per node). Zeroes only the <=3 gap slots, resets cur in place.
__global__ __launch_bounds__(256) void alloc_kernel(
    int* __restrict__ deg_cur,        // in: degree, out: 0 (reused as cur)
    int* __restrict__ gcount,
    int* __restrict__ off_s, int* __restrict__ off_pe,
    int* __restrict__ src_s, float2* __restrict__ w2_s)
{
    const int node = blockIdx.x * blockDim.x + threadIdx.x;
    const int lane = threadIdx.x & 63;
    const bool ok = node < N_NODES;
    int d  = ok ? deg_cur[node] : 0;
    int pd = (d + 3) & ~3;
    int pref = pd;
#pragma unroll
    for (int o = 1; o < 64; o <<= 1) {
        int v = __shfl_up(pref, o);
        if (lane >= o) pref += v;
    }
    int tot = __shfl(pref, 63);
    int base = 0;
    if (lane == 63) base = atomicAdd(gcount, tot);
    base = __shfl(base, 63);
    const int start = base + pref - pd;
    if (ok) {
        off_s[node]  = start;
        off_pe[node] = start + pd;
        deg_cur[node] = 0;                    // becomes scatter's cur
        for (int k = d; k < pd; ++k) {        // zero gap slots only
            src_s[start + k] = 0;
            w2_s[start + k]  = make_float2(0.f, 0.f);
        }
    }
}

// Scatter edges into dst-sorted fused arrays; weights interleaved as float2.
__global__ void scatter_kernel(const int* __restrict__ dst, const int* __restrict__ src,
                               const float* __restrict__ self_w, const float* __restrict__ ppi_w,
                               const int* __restrict__ off_s, int* __restrict__ cur,
                               int* __restrict__ src_s, float2* __restrict__ w2_s) {
    int e = blockIdx.x * blockDim.x + threadIdx.x;
    if (e < N_EDGES) {
        int d = dst[e];
        int p = off_s[d] + atomicAdd(&cur[d], 1);
        src_s[p] = src[e];
        w2_s[p]  = make_float2(ppi_w[e], self_w[e]);   // (.x = ppi, .y = self)
    }
}

// ---------------- MFMA GEMM, swapped operands ----------------
// D = (W-pack as A) * (node rows as B): D row = output dim, D col = node.
// Each lane holds 4 CONSECUTIVE output dims of one node -> contiguous stores.
template<int K, int G, bool XF32, bool RELU, bool ADD_RES, bool WRITE_F32>
__global__ __launch_bounds__(256) void mfma_gemm_kernel(
    const void* __restrict__ Av, const ushort_t* __restrict__ Bp,
    const float* __restrict__ bias, const ushort_t* __restrict__ res_b,
    float* __restrict__ Cf, ushort_t* __restrict__ Cb,
    int Nreal, int Mstore)
{
    constexpr int CHN = K / 32;
    const int lane = threadIdx.x & 63;
    const int w    = threadIdx.x >> 6;
    const int r0   = blockIdx.y * 64;
    const int lr   = lane & 15;
    const int lq   = lane >> 4;

    // hoist all node-side fragments (B operand); reused across the G dim-tiles
    bf16x8 bf[4][CHN];
    if constexpr (!XF32) {
#pragma unroll
        for (int t = 0; t < 4; ++t) {
            const ushort_t* p = (const ushort_t*)Av + (size_t)(r0 + t * 16 + lr) * K + lq * 8;
#pragma unroll
            for (int c = 0; c < CHN; ++c)
                bf[t][c] = *(const bf16x8*)(p + c * 32);
        }
    } else {
#pragma unroll
        for (int t = 0; t < 4; ++t) {
            const int row = r0 + t * 16 + lr;
            const float* p = (const float*)Av + (size_t)row * K + lq * 8;
            const bool ok = row < N_NODES;
#pragma unroll
            for (int c = 0; c < CHN; ++c) {
                u32x4 uu = {0u, 0u, 0u, 0u};
                if (ok) {
                    float4 f0 = ((const float4*)(p + c * 32))[0];
                    float4 f1 = ((const float4*)(p + c * 32))[1];
                    uu.x = cvt_pk_bf16(f0.x, f0.y);
                    uu.y = cvt_pk_bf16(f0.z, f0.w);
                    uu.z = cvt_pk_bf16(f1.x, f1.y);
                    uu.w = cvt_pk_bf16(f1.z, f1.w);
                }
                bf[t][c] = __builtin_bit_cast(bf16x8, uu);
            }
        }
    }

    for (int g = 0; g < G; ++g) {
        const int dt = (blockIdx.x * G + g) * 4 + w;   // output-dim tile (16 dims)
        f32x4 acc[4] = {f32x4{0,0,0,0}, f32x4{0,0,0,0}, f32x4{0,0,0,0}, f32x4{0,0,0,0}};
#pragma unroll
        for (int c = 0; c < CHN; ++c) {
            bf16x8 afrag = *(const bf16x8*)(Bp + ((size_t)(dt * CHN + c) * 64 + lane) * 8);
#pragma unroll
            for (int t = 0; t < 4; ++t)
                acc[t] = __builtin_amdgcn_mfma_f32_16x16x32_bf16(afrag, bf[t][c], acc[t], 0, 0, 0);
        }

        const int d0 = dt * 16 + lq * 4;               // first of 4 consecutive out dims
        float bv[4];
        if (d0 + 3 < Nreal) {
            const float4 b4 = *(const float4*)(bias + d0);
            bv[0] = b4.x; bv[1] = b4.y; bv[2] = b4.z; bv[3] = b4.w;
        } else {
#pragma unroll
            for (int i = 0; i < 4; ++i) bv[i] = (d0 + i < Nreal) ? bias[d0 + i] : 0.f;
        }
#pragma unroll
        for (int t = 0; t < 4; ++t) {
            const int node = r0 + t * 16 + lr;
            if (node >= Mstore) continue;
            float v[4];
#pragma unroll
            for (int i = 0; i < 4; ++i) {
                v[i] = acc[t][i] + bv[i];
                if (RELU) v[i] = fmaxf(v[i], 0.f);
            }
            if (ADD_RES) {
                const uint2 rr = *(const uint2*)(res_b + (size_t)node * DH + d0);
                v[0] += bf16_lo(rr.x); v[1] += bf16_hi(rr.x);
                v[2] += bf16_lo(rr.y); v[3] += bf16_hi(rr.y);
            }
            if (WRITE_F32) {
                float* q = Cf + (size_t)node * Nreal + d0;
                if (d0 + 3 < Nreal) {
                    f32x4 o4; o4.x = v[0]; o4.y = v[1]; o4.z = v[2]; o4.w = v[3];
                    __builtin_nontemporal_store(o4, (f32x4*)q);   // streamed, never re-read
                } else {
#pragma unroll
                    for (int i = 0; i < 4; ++i)
                        if (d0 + i < Nreal) q[i] = v[i];
                }
            } else {
                uint2 pp;
                pp.x = cvt_pk_bf16(v[0], v[1]);
                pp.y = cvt_pk_bf16(v[2], v[3]);
                *(uint2*)(Cb + (size_t)node * DH + d0) = pp;
            }
        }
    }
}

// ---------------- aggregation: 1 wave/node, 2 dims/lane, bf16 h ----------------
// Segments 4-padded; 8-edge main body keeps 8 gathers in flight.
__global__ __launch_bounds__(256) void aggregate_kernel(
    const ushort_t* __restrict__ hb,
    const int* __restrict__ off_s, const int* __restrict__ off_pe,
    const int* __restrict__ src_s, const float2* __restrict__ w2_s,
    ushort_t* __restrict__ agg_b, ushort_t* __restrict__ res_b)
{
    const int node = blockIdx.x * 4 + (threadIdx.x >> 6);
    const int t = threadIdx.x & 63;
    float aa0 = 0.f, aa1 = 0.f, rr0 = 0.f, rr1 = 0.f;
    if (node < N_NODES) {
        const int lo = off_s[node], hi = off_pe[node];
        int i = lo;
        for (; i + 8 <= hi; i += 8) {
            const int4   sA = *(const int4*)(src_s + i);
            const int4   sB = *(const int4*)(src_s + i + 4);
            const float4 w0 = *(const float4*)(w2_s + i);
            const float4 w1 = *(const float4*)(w2_s + i + 2);
            const float4 w2 = *(const float4*)(w2_s + i + 4);
            const float4 w3 = *(const float4*)(w2_s + i + 6);
            unsigned u0 = *(const unsigned*)(hb + (size_t)sA.x * DH + 2 * t);
            unsigned u1 = *(const unsigned*)(hb + (size_t)sA.y * DH + 2 * t);
            unsigned u2 = *(const unsigned*)(hb + (size_t)sA.z * DH + 2 * t);
            unsigned u3 = *(const unsigned*)(hb + (size_t)sA.w * DH + 2 * t);
            unsigned u4 = *(const unsigned*)(hb + (size_t)sB.x * DH + 2 * t);
            unsigned u5 = *(const unsigned*)(hb + (size_t)sB.y * DH + 2 * t);
            unsigned u6 = *(const unsigned*)(hb + (size_t)sB.z * DH + 2 * t);
            unsigned u7 = *(const unsigned*)(hb + (size_t)sB.w * DH + 2 * t);
            float a0 = bf16_lo(u0), b0 = bf16_hi(u0);
            float a1 = bf16_lo(u1), b1 = bf16_hi(u1);
            float a2 = bf16_lo(u2), b2 = bf16_hi(u2);
            float a3 = bf16_lo(u3), b3 = bf16_hi(u3);
            float a4 = bf16_lo(u4), b4 = bf16_hi(u4);
            float a5 = bf16_lo(u5), b5 = bf16_hi(u5);
            float a6 = bf16_lo(u6), b6 = bf16_hi(u6);
            float a7 = bf16_lo(u7), b7 = bf16_hi(u7);
            aa0 += w0.x * a0 + w0.z * a1 + w1.x * a2 + w1.z * a3
                 + w2.x * a4 + w2.z * a5 + w3.x * a6 + w3.z * a7;
            aa1 += w0.x * b0 + w0.z * b1 + w1.x * b2 + w1.z * b3
                 + w2.x * b4 + w2.z * b5 + w3.x * b6 + w3.z * b7;
            rr0 += w0.y * a0 + w0.w * a1 + w1.y * a2 + w1.w * a3
                 + w2.y * a4 + w2.w * a5 + w3.y * a6 + w3.w * a7;
            rr1 += w0.y * b0 + w0.w * b1 + w1.y * b2 + w1.w * b3
                 + w2.y * b4 + w2.w * b5 + w3.y * b6 + w3.w * b7;
        }
        for (; i < hi; i += 4) {
            const int4   s4 = *(const int4*)(src_s + i);
            const float4 wa = *(const float4*)(w2_s + i);
            const float4 wb = *(const float4*)(w2_s + i + 2);
            unsigned u0 = *(const unsigned*)(hb + (size_t)s4.x * DH + 2 * t);
            unsigned u1 = *(const unsigned*)(hb + (size_t)s4.y * DH + 2 * t);
            unsigned u2 = *(const unsigned*)(hb + (size_t)s4.z * DH + 2 * t);
            unsigned u3 = *(const unsigned*)(hb + (size_t)s4.w * DH + 2 * t);
            float a0 = bf16_lo(u0), b0 = bf16_hi(u0);
            float a1 = bf16_lo(u1), b1 = bf16_hi(u1);
            float a2 = bf16_lo(u2), b2 = bf16_hi(u2);
            float a3 = bf16_lo(u3), b3 = bf16_hi(u3);
            aa0 += wa.x * a0 + wa.z * a1 + wb.x * a2 + wb.z * a3;
            aa1 += wa.x * b0 + wa.z * b1 + wb.x * b2 + wb.z * b3;
            rr0 += wa.y * a0 + wa.w * a1 + wb.y * a2 + wb.w * a3;
            rr1 += wa.y * b0 + wa.w * b1 + wb.y * b2 + wb.w * b3;
        }
    }
    unsigned pa = cvt_pk_bf16(aa0, aa1);
    unsigned pr = cvt_pk_bf16(rr0, rr1);
    *(unsigned*)(agg_b + (size_t)node * DH + 2 * t) = pa;
    *(unsigned*)(res_b + (size_t)node * DH + 2 * t) = pr;
}

// ---------------- launch ----------------

extern "C" void kernel_launch(void* const* d_in, const int* in_sizes, int n_in,
                              void* d_out, int out_size, void* d_ws, size_t ws_size,
                              hipStream_t stream) {
    const float* x      = (const float*)d_in[0];
    const int*   src    = (const int*)d_in[1];
    const int*   dst    = (const int*)d_in[2];
    const float* self_w = (const float*)d_in[3];
    const float* ppi_w  = (const float*)d_in[4];
    const float* W_in   = (const float*)d_in[5];
    const float* b_in   = (const float*)d_in[6];
    const float* W1     = (const float*)d_in[7];
    const float* b1     = (const float*)d_in[8];
    const float* W2     = (const float*)d_in[9];
    const float* b2     = (const float*)d_in[10];
    const float* W_out  = (const float*)d_in[11];
    const float* b_out  = (const float*)d_in[12];
    float* out = (float*)d_out;

    char* ws = (char*)d_ws;
    size_t o = 0;
    auto alloc = [&](size_t bytes) { void* p = ws + o; o += (bytes + 255) & ~(size_t)255; return p; };

    ushort_t* hb     = (ushort_t*)alloc((size_t)M_PAD * DH * 2);   // 12.8 MB
    ushort_t* agg_b  = (ushort_t*)alloc((size_t)M_PAD * DH * 2);   // 12.8 MB
    ushort_t* res_b  = (ushort_t*)alloc((size_t)M_PAD * DH * 2);   // 12.8 MB
    int*      degz   = (int*)alloc((size_t)(N_NODES + 1) * 4);     // deg/cur + gcount
    int*      gcount = degz + N_NODES;
    int*      off_s  = (int*)alloc((size_t)N_NODES * 4);
    int*      off_pe = (int*)alloc((size_t)N_NODES * 4);
    int*      src_s  = (int*)alloc((size_t)E_PAD * 4);
    float2*   w2_s   = (float2*)alloc((size_t)E_PAD * 8);
    ushort_t* Bp_in  = (ushort_t*)alloc((size_t)T_IN * 8 * 2);
    ushort_t* Bp_1   = (ushort_t*)alloc((size_t)T_L * 8 * 2);
    ushort_t* Bp_2   = (ushort_t*)alloc((size_t)T_L * 8 * 2);
    ushort_t* Bp_out = (ushort_t*)alloc((size_t)T_OUT * 8 * 2);

    // CSR build: deg count (+ fused weight pack), wave-atomic alloc, scatter
    (void)hipMemsetAsync(degz, 0, (size_t)(N_NODES + 1) * 4, stream);
    count_pack_kernel<<<EB + PB, 256, 0, stream>>>(dst, degz, W_in, W1, W2, W_out,
                                                   Bp_in, Bp_1, Bp_2, Bp_out);
    alloc_kernel<<<(N_NODES + 255) / 256, 256, 0, stream>>>(degz, gcount, off_s, off_pe,
                                                            src_s, w2_s);
    scatter_kernel<<<EB, 256, 0, stream>>>(dst, src, self_w, ppi_w, off_s, degz, src_s, w2_s);

    const dim3 g_h(1, M_PAD / 64);   // DH GEMMs: 8 dim-tiles, G=2 x 4 waves
    const dim3 g_o(4, M_PAD / 64);   // out GEMM: 64 dim-tiles, G=4

    // input linear: hb = relu(x @ W_in + b_in)   (reads f32 x directly)
    mfma_gemm_kernel<DIN, 2, true, true, false, false>
        <<<g_h, 256, 0, stream>>>(x, Bp_in, b_in, nullptr, nullptr, hb, DH, M_PAD);

    // layer 1
    aggregate_kernel<<<M_PAD / 4, 256, 0, stream>>>(hb, off_s, off_pe, src_s, w2_s, agg_b, res_b);
    mfma_gemm_kernel<DH, 2, false, true, true, false>
        <<<g_h, 256, 0, stream>>>(agg_b, Bp_1, b1, res_b, nullptr, hb, DH, M_PAD);

    // layer 2
    aggregate_kernel<<<M_PAD / 4, 256, 0, stream>>>(hb, off_s, off_pe, src_s, w2_s, agg_b, res_b);
    mfma_gemm_kernel<DH, 2, false, true, true, false>
        <<<g_h, 256, 0, stream>>>(agg_b, Bp_2, b2, res_b, nullptr, hb, DH, M_PAD);

    // output linear: out = hb @ W_out + b_out  (nontemporal float4 stores)
    mfma_gemm_kernel<DH, 4, false, false, false, true>
        <<<g_o, 256, 0, stream>>>(hb, Bp_out, b_out, nullptr, out, nullptr, NL, N_NODES);
}

// Round 4
// 546.636 us; speedup vs baseline: 1.3185x; 1.1021x over previous
//
#include <hip/hip_runtime.h>

#define N_NODES 50000
#define M_PAD   50048          // nodes padded to multiple of 64
#define N_EDGES 800000
#define E_PAD   1000000        // >= N_EDGES + 3*N_NODES (4-padded segments)
#define DIN 256
#define DH  128
#define NL  1000
#define NL_PAD 1024

typedef unsigned short ushort_t;
typedef __attribute__((ext_vector_type(8))) short bf16x8;
typedef __attribute__((ext_vector_type(4))) float f32x4;
typedef __attribute__((ext_vector_type(4))) unsigned int u32x4;

__device__ __forceinline__ ushort_t f32_to_bf16_rne(float f) {
    unsigned int u = __float_as_uint(f);
    unsigned int r = (u + 0x7FFFu + ((u >> 16) & 1u)) >> 16;
    return (ushort_t)r;
}
// packs (lo,hi) f32 -> 2x bf16 in one instr (no builtin on gfx950; inline asm)
__device__ __forceinline__ unsigned cvt_pk_bf16(float lo, float hi) {
    unsigned r;
    asm("v_cvt_pk_bf16_f32 %0, %1, %2" : "=v"(r) : "v"(lo), "v"(hi));
    return r;
}
__device__ __forceinline__ float bf16_lo(unsigned u) { return __uint_as_float(u << 16); }
__device__ __forceinline__ float bf16_hi(unsigned u) { return __uint_as_float(u & 0xFFFF0000u); }

// ---------------- fused B-operand pack (fragment-contiguous) ----------------
__device__ __forceinline__ void pack_one(const float* __restrict__ W, ushort_t* __restrict__ Bp,
                                         int K, int Nreal, int t) {
    const int CHN = K / 32;
    int lane = t & 63;
    int c = (t >> 6) % CHN;
    int nt = (t >> 6) / CHN;
    int n = nt * 16 + (lane & 15);
    int kb = c * 32 + (lane >> 4) * 8;
    ushort_t* p = Bp + (size_t)t * 8;
#pragma unroll
    for (int j = 0; j < 8; ++j)
        p[j] = (n < Nreal) ? f32_to_bf16_rne(W[(size_t)(kb + j) * Nreal + n]) : (ushort_t)0;
}

#define T_IN  ((DH / 16) * (DIN / 32) * 64)        // 4096
#define T_L   ((DH / 16) * (DH / 32) * 64)         // 2048
#define T_OUT ((NL_PAD / 16) * (DH / 32) * 64)     // 16384
#define T_ALL (T_IN + 2 * T_L + T_OUT)             // 24576
#define EB    ((N_EDGES + 255) / 256)              // 3125 (exact: 3125*256 = 800000)
#define PB    (T_ALL / 256)                        // 96

// ---------------- CSR build ----------------

// blocks [0, EB): degree count.  blocks [EB, EB+PB): weight packing (independent).
__global__ void count_pack_kernel(const int* __restrict__ dst, int* __restrict__ deg,
                                  const float* __restrict__ W_in, const float* __restrict__ W1,
                                  const float* __restrict__ W2, const float* __restrict__ W_out,
                                  ushort_t* __restrict__ Bp_in, ushort_t* __restrict__ Bp_1,
                                  ushort_t* __restrict__ Bp_2, ushort_t* __restrict__ Bp_out) {
    if (blockIdx.x < EB) {
        int e = blockIdx.x * blockDim.x + threadIdx.x;
        if (e < N_EDGES) atomicAdd(&deg[dst[e]], 1);
    } else {
        int tid = (blockIdx.x - EB) * blockDim.x + threadIdx.x;
        if (tid < T_IN) pack_one(W_in, Bp_in, DIN, DH, tid);
        else if (tid < T_IN + T_L) pack_one(W1, Bp_1, DH, DH, tid - T_IN);
        else if (tid < T_IN + 2 * T_L) pack_one(W2, Bp_2, DH, DH, tid - T_IN - T_L);
        else if (tid < T_ALL) pack_one(W_out, Bp_out, DH, NL, tid - T_IN - 2 * T_L);
    }
}

// Wave-atomic segment allocation: replaces the single-block global scan.
__global__ __launch_bounds__(256) void alloc_kernel(
    int* __restrict__ deg_cur,        // in: degree, out: 0 (reused as cur)
    int* __restrict__ gcount,
    int* __restrict__ off_s, int* __restrict__ off_pe,
    int* __restrict__ src_s, float2* __restrict__ w2_s)
{
    const int node = blockIdx.x * blockDim.x + threadIdx.x;
    const int lane = threadIdx.x & 63;
    const bool ok = node < N_NODES;
    int d  = ok ? deg_cur[node] : 0;
    int pd = (d + 3) & ~3;
    int pref = pd;
#pragma unroll
    for (int o = 1; o < 64; o <<= 1) {
        int v = __shfl_up(pref, o);
        if (lane >= o) pref += v;
    }
    int tot = __shfl(pref, 63);
    int base = 0;
    if (lane == 63) base = atomicAdd(gcount, tot);
    base = __shfl(base, 63);
    const int start = base + pref - pd;
    if (ok) {
        off_s[node]  = start;
        off_pe[node] = start + pd;
        deg_cur[node] = 0;                    // becomes scatter's cur
        for (int k = d; k < pd; ++k) {        // zero gap slots only
            src_s[start + k] = 0;
            w2_s[start + k]  = make_float2(0.f, 0.f);
        }
    }
}

// Scatter edges into dst-sorted fused arrays; weights interleaved as float2.
__global__ void scatter_kernel(const int* __restrict__ dst, const int* __restrict__ src,
                               const float* __restrict__ self_w, const float* __restrict__ ppi_w,
                               const int* __restrict__ off_s, int* __restrict__ cur,
                               int* __restrict__ src_s, float2* __restrict__ w2_s) {
    int e = blockIdx.x * blockDim.x + threadIdx.x;
    if (e < N_EDGES) {
        int d = dst[e];
        int p = off_s[d] + atomicAdd(&cur[d], 1);
        src_s[p] = src[e];
        w2_s[p]  = make_float2(ppi_w[e], self_w[e]);   // (.x = ppi, .y = self)
    }
}

// ---------------- MFMA GEMM, swapped operands (hidden layers + input) -------
template<int K, int G, bool XF32, bool RELU, bool ADD_RES>
__global__ __launch_bounds__(256) void mfma_gemm_kernel(
    const void* __restrict__ Av, const ushort_t* __restrict__ Bp,
    const float* __restrict__ bias, const ushort_t* __restrict__ res_b,
    ushort_t* __restrict__ Cb, int Nreal, int Mstore)
{
    constexpr int CHN = K / 32;
    const int lane = threadIdx.x & 63;
    const int w    = threadIdx.x >> 6;
    const int r0   = blockIdx.y * 64;
    const int lr   = lane & 15;
    const int lq   = lane >> 4;

    // hoist all node-side fragments (B operand); reused across the G dim-tiles
    bf16x8 bf[4][CHN];
    if constexpr (!XF32) {
#pragma unroll
        for (int t = 0; t < 4; ++t) {
            const ushort_t* p = (const ushort_t*)Av + (size_t)(r0 + t * 16 + lr) * K + lq * 8;
#pragma unroll
            for (int c = 0; c < CHN; ++c)
                bf[t][c] = *(const bf16x8*)(p + c * 32);
        }
    } else {
#pragma unroll
        for (int t = 0; t < 4; ++t) {
            const int row = r0 + t * 16 + lr;
            const float* p = (const float*)Av + (size_t)row * K + lq * 8;
            const bool ok = row < N_NODES;
#pragma unroll
            for (int c = 0; c < CHN; ++c) {
                u32x4 uu = {0u, 0u, 0u, 0u};
                if (ok) {
                    float4 f0 = ((const float4*)(p + c * 32))[0];
                    float4 f1 = ((const float4*)(p + c * 32))[1];
                    uu.x = cvt_pk_bf16(f0.x, f0.y);
                    uu.y = cvt_pk_bf16(f0.z, f0.w);
                    uu.z = cvt_pk_bf16(f1.x, f1.y);
                    uu.w = cvt_pk_bf16(f1.z, f1.w);
                }
                bf[t][c] = __builtin_bit_cast(bf16x8, uu);
            }
        }
    }

    for (int g = 0; g < G; ++g) {
        const int dt = (blockIdx.x * G + g) * 4 + w;   // output-dim tile (16 dims)
        f32x4 acc[4] = {f32x4{0,0,0,0}, f32x4{0,0,0,0}, f32x4{0,0,0,0}, f32x4{0,0,0,0}};
#pragma unroll
        for (int c = 0; c < CHN; ++c) {
            bf16x8 afrag = *(const bf16x8*)(Bp + ((size_t)(dt * CHN + c) * 64 + lane) * 8);
#pragma unroll
            for (int t = 0; t < 4; ++t)
                acc[t] = __builtin_amdgcn_mfma_f32_16x16x32_bf16(afrag, bf[t][c], acc[t], 0, 0, 0);
        }

        const int d0 = dt * 16 + lq * 4;               // first of 4 consecutive out dims
        const float4 b4 = *(const float4*)(bias + d0); // Nreal==DH here, always in-bounds
        float bv[4] = {b4.x, b4.y, b4.z, b4.w};
#pragma unroll
        for (int t = 0; t < 4; ++t) {
            const int node = r0 + t * 16 + lr;
            if (node >= Mstore) continue;
            float v[4];
#pragma unroll
            for (int i = 0; i < 4; ++i) {
                v[i] = acc[t][i] + bv[i];
                if (RELU) v[i] = fmaxf(v[i], 0.f);
            }
            if (ADD_RES) {
                const uint2 rr = *(const uint2*)(res_b + (size_t)node * DH + d0);
                v[0] += bf16_lo(rr.x); v[1] += bf16_hi(rr.x);
                v[2] += bf16_lo(rr.y); v[3] += bf16_hi(rr.y);
            }
            uint2 pp;
            pp.x = cvt_pk_bf16(v[0], v[1]);
            pp.y = cvt_pk_bf16(v[2], v[3]);
            *(uint2*)(Cb + (size_t)node * DH + d0) = pp;
        }
    }
}

// ---------------- output GEMM with LDS-staged contiguous stores -------------
// Each block: 64 nodes x 256 labels. Compute phase identical to the generic
// GEMM; results staged in LDS (row stride 260 f32 -> 2-way bank alias, free),
// then swept out as 1024-B contiguous per-wave stores (full 128-B lines).
__global__ __launch_bounds__(256) void mfma_out_kernel(
    const ushort_t* __restrict__ hb, const ushort_t* __restrict__ Bp,
    const float* __restrict__ bias, float* __restrict__ out)
{
    constexpr int CHN = DH / 32;                       // 4
    __shared__ float cst[64][260];                     // 65 KB
    const int lane = threadIdx.x & 63;
    const int w    = threadIdx.x >> 6;
    const int r0   = blockIdx.y * 64;
    const int lr   = lane & 15;
    const int lq   = lane >> 4;

    bf16x8 bf[4][CHN];
#pragma unroll
    for (int t = 0; t < 4; ++t) {
        const ushort_t* p = hb + (size_t)(r0 + t * 16 + lr) * DH + lq * 8;
#pragma unroll
        for (int c = 0; c < CHN; ++c)
            bf[t][c] = *(const bf16x8*)(p + c * 32);
    }

#pragma unroll
    for (int g = 0; g < 4; ++g) {
        const int dt = (blockIdx.x * 4 + g) * 4 + w;   // global 16-label tile
        f32x4 acc[4] = {f32x4{0,0,0,0}, f32x4{0,0,0,0}, f32x4{0,0,0,0}, f32x4{0,0,0,0}};
#pragma unroll
        for (int c = 0; c < CHN; ++c) {
            bf16x8 afrag = *(const bf16x8*)(Bp + ((size_t)(dt * CHN + c) * 64 + lane) * 8);
#pragma unroll
            for (int t = 0; t < 4; ++t)
                acc[t] = __builtin_amdgcn_mfma_f32_16x16x32_bf16(afrag, bf[t][c], acc[t], 0, 0, 0);
        }

        const int d0 = dt * 16 + lq * 4;               // global label index
        float bv[4];
        if (d0 + 3 < NL) {
            const float4 b4 = *(const float4*)(bias + d0);
            bv[0] = b4.x; bv[1] = b4.y; bv[2] = b4.z; bv[3] = b4.w;
        } else {
#pragma unroll
            for (int i = 0; i < 4; ++i) bv[i] = (d0 + i < NL) ? bias[d0 + i] : 0.f;
        }
        const int cl = ((g * 4 + w) * 16) + lq * 4;    // local col in the 256-wide tile
#pragma unroll
        for (int t = 0; t < 4; ++t) {
            const int rl = t * 16 + lr;
#pragma unroll
            for (int i = 0; i < 4; ++i)
                cst[rl][cl + i] = acc[t][i] + bv[i];
        }
    }
    __syncthreads();

    // store sweep: one 1024-B contiguous wave store per node row chunk
    const int colbase = blockIdx.x * 256;
    const int c = lane * 4;                            // local col (f32)
#pragma unroll
    for (int r = 0; r < 16; ++r) {
        const int rl = w * 16 + r;
        const int node = r0 + rl;
        if (node < N_NODES && colbase + c < NL) {
            float4 o4;
            o4.x = cst[rl][c]; o4.y = cst[rl][c + 1];
            o4.z = cst[rl][c + 2]; o4.w = cst[rl][c + 3];
            *(float4*)(out + (size_t)node * NL + colbase + c) = o4;
        }
    }
}

// ---------------- aggregation: 1 wave/node, 2 dims/lane, bf16 h ----------------
__global__ __launch_bounds__(256) void aggregate_kernel(
    const ushort_t* __restrict__ hb,
    const int* __restrict__ off_s, const int* __restrict__ off_pe,
    const int* __restrict__ src_s, const float2* __restrict__ w2_s,
    ushort_t* __restrict__ agg_b, ushort_t* __restrict__ res_b)
{
    const int node = blockIdx.x * 4 + (threadIdx.x >> 6);
    const int t = threadIdx.x & 63;
    float aa0 = 0.f, aa1 = 0.f, rr0 = 0.f, rr1 = 0.f;
    if (node < N_NODES) {
        const int lo = off_s[node], hi = off_pe[node];
        int i = lo;
        for (; i + 8 <= hi; i += 8) {
            const int4   sA = *(const int4*)(src_s + i);
            const int4   sB = *(const int4*)(src_s + i + 4);
            const float4 w0 = *(const float4*)(w2_s + i);
            const float4 w1 = *(const float4*)(w2_s + i + 2);
            const float4 w2 = *(const float4*)(w2_s + i + 4);
            const float4 w3 = *(const float4*)(w2_s + i + 6);
            unsigned u0 = *(const unsigned*)(hb + (size_t)sA.x * DH + 2 * t);
            unsigned u1 = *(const unsigned*)(hb + (size_t)sA.y * DH + 2 * t);
            unsigned u2 = *(const unsigned*)(hb + (size_t)sA.z * DH + 2 * t);
            unsigned u3 = *(const unsigned*)(hb + (size_t)sA.w * DH + 2 * t);
            unsigned u4 = *(const unsigned*)(hb + (size_t)sB.x * DH + 2 * t);
            unsigned u5 = *(const unsigned*)(hb + (size_t)sB.y * DH + 2 * t);
            unsigned u6 = *(const unsigned*)(hb + (size_t)sB.z * DH + 2 * t);
            unsigned u7 = *(const unsigned*)(hb + (size_t)sB.w * DH + 2 * t);
            float a0 = bf16_lo(u0), b0 = bf16_hi(u0);
            float a1 = bf16_lo(u1), b1 = bf16_hi(u1);
            float a2 = bf16_lo(u2), b2 = bf16_hi(u2);
            float a3 = bf16_lo(u3), b3 = bf16_hi(u3);
            float a4 = bf16_lo(u4), b4 = bf16_hi(u4);
            float a5 = bf16_lo(u5), b5 = bf16_hi(u5);
            float a6 = bf16_lo(u6), b6 = bf16_hi(u6);
            float a7 = bf16_lo(u7), b7 = bf16_hi(u7);
            aa0 += w0.x * a0 + w0.z * a1 + w1.x * a2 + w1.z * a3
                 + w2.x * a4 + w2.z * a5 + w3.x * a6 + w3.z * a7;
            aa1 += w0.x * b0 + w0.z * b1 + w1.x * b2 + w1.z * b3
                 + w2.x * b4 + w2.z * b5 + w3.x * b6 + w3.z * b7;
            rr0 += w0.y * a0 + w0.w * a1 + w1.y * a2 + w1.w * a3
                 + w2.y * a4 + w2.w * a5 + w3.y * a6 + w3.w * a7;
            rr1 += w0.y * b0 + w0.w * b1 + w1.y * b2 + w1.w * b3
                 + w2.y * b4 + w2.w * b5 + w3.y * b6 + w3.w * b7;
        }
        for (; i < hi; i += 4) {
            const int4   s4 = *(const int4*)(src_s + i);
            const float4 wa = *(const float4*)(w2_s + i);
            const float4 wb = *(const float4*)(w2_s + i + 2);
            unsigned u0 = *(const unsigned*)(hb + (size_t)s4.x * DH + 2 * t);
            unsigned u1 = *(const unsigned*)(hb + (size_t)s4.y * DH + 2 * t);
            unsigned u2 = *(const unsigned*)(hb + (size_t)s4.z * DH + 2 * t);
            unsigned u3 = *(const unsigned*)(hb + (size_t)s4.w * DH + 2 * t);
            float a0 = bf16_lo(u0), b0 = bf16_hi(u0);
            float a1 = bf16_lo(u1), b1 = bf16_hi(u1);
            float a2 = bf16_lo(u2), b2 = bf16_hi(u2);
            float a3 = bf16_lo(u3), b3 = bf16_hi(u3);
            aa0 += wa.x * a0 + wa.z * a1 + wb.x * a2 + wb.z * a3;
            aa1 += wa.x * b0 + wa.z * b1 + wb.x * b2 + wb.z * b3;
            rr0 += wa.y * a0 + wa.w * a1 + wb.y * a2 + wb.w * a3;
            rr1 += wa.y * b0 + wa.w * b1 + wb.y * b2 + wb.w * b3;
        }
    }
    unsigned pa = cvt_pk_bf16(aa0, aa1);
    unsigned pr = cvt_pk_bf16(rr0, rr1);
    *(unsigned*)(agg_b + (size_t)node * DH + 2 * t) = pa;
    *(unsigned*)(res_b + (size_t)node * DH + 2 * t) = pr;
}

// ---------------- launch ----------------

extern "C" void kernel_launch(void* const* d_in, const int* in_sizes, int n_in,
                              void* d_out, int out_size, void* d_ws, size_t ws_size,
                              hipStream_t stream) {
    const float* x      = (const float*)d_in[0];
    const int*   src    = (const int*)d_in[1];
    const int*   dst    = (const int*)d_in[2];
    const float* self_w = (const float*)d_in[3];
    const float* ppi_w  = (const float*)d_in[4];
    const float* W_in   = (const float*)d_in[5];
    const float* b_in   = (const float*)d_in[6];
    const float* W1     = (const float*)d_in[7];
    const float* b1     = (const float*)d_in[8];
    const float* W2     = (const float*)d_in[9];
    const float* b2     = (const float*)d_in[10];
    const float* W_out  = (const float*)d_in[11];
    const float* b_out  = (const float*)d_in[12];
    float* out = (float*)d_out;

    char* ws = (char*)d_ws;
    size_t o = 0;
    auto alloc = [&](size_t bytes) { void* p = ws + o; o += (bytes + 255) & ~(size_t)255; return p; };

    ushort_t* hb     = (ushort_t*)alloc((size_t)M_PAD * DH * 2);   // 12.8 MB
    ushort_t* agg_b  = (ushort_t*)alloc((size_t)M_PAD * DH * 2);   // 12.8 MB
    ushort_t* res_b  = (ushort_t*)alloc((size_t)M_PAD * DH * 2);   // 12.8 MB
    int*      degz   = (int*)alloc((size_t)(N_NODES + 1) * 4);     // deg/cur + gcount
    int*      gcount = degz + N_NODES;
    int*      off_s  = (int*)alloc((size_t)N_NODES * 4);
    int*      off_pe = (int*)alloc((size_t)N_NODES * 4);
    int*      src_s  = (int*)alloc((size_t)E_PAD * 4);
    float2*   w2_s   = (float2*)alloc((size_t)E_PAD * 8);
    ushort_t* Bp_in  = (ushort_t*)alloc((size_t)T_IN * 8 * 2);
    ushort_t* Bp_1   = (ushort_t*)alloc((size_t)T_L * 8 * 2);
    ushort_t* Bp_2   = (ushort_t*)alloc((size_t)T_L * 8 * 2);
    ushort_t* Bp_out = (ushort_t*)alloc((size_t)T_OUT * 8 * 2);

    // CSR build: deg count (+ fused weight pack), wave-atomic alloc, scatter
    (void)hipMemsetAsync(degz, 0, (size_t)(N_NODES + 1) * 4, stream);
    count_pack_kernel<<<EB + PB, 256, 0, stream>>>(dst, degz, W_in, W1, W2, W_out,
                                                   Bp_in, Bp_1, Bp_2, Bp_out);
    alloc_kernel<<<(N_NODES + 255) / 256, 256, 0, stream>>>(degz, gcount, off_s, off_pe,
                                                            src_s, w2_s);
    scatter_kernel<<<EB, 256, 0, stream>>>(dst, src, self_w, ppi_w, off_s, degz, src_s, w2_s);

    const dim3 g_h(1, M_PAD / 64);   // DH GEMMs: 8 dim-tiles, G=2 x 4 waves
    const dim3 g_o(4, M_PAD / 64);   // out GEMM: 4 x 256-label chunks

    // input linear: hb = relu(x @ W_in + b_in)   (reads f32 x directly)
    mfma_gemm_kernel<DIN, 2, true, true, false>
        <<<g_h, 256, 0, stream>>>(x, Bp_in, b_in, nullptr, hb, DH, M_PAD);

    // layer 1
    aggregate_kernel<<<M_PAD / 4, 256, 0, stream>>>(hb, off_s, off_pe, src_s, w2_s, agg_b, res_b);
    mfma_gemm_kernel<DH, 2, false, true, true>
        <<<g_h, 256, 0, stream>>>(agg_b, Bp_1, b1, res_b, hb, DH, M_PAD);

    // layer 2
    aggregate_kernel<<<M_PAD / 4, 256, 0, stream>>>(hb, off_s, off_pe, src_s, w2_s, agg_b, res_b);
    mfma_gemm_kernel<DH, 2, false, true, true>
        <<<g_h, 256, 0, stream>>>(agg_b, Bp_2, b2, res_b, hb, DH, M_PAD);

    // output linear: out = hb @ W_out + b_out  (LDS-staged contiguous stores)
    mfma_out_kernel<<<g_o, 256, 0, stream>>>(hb, Bp_out, b_out, out);
}